// Round 7
// baseline (235.012 us; speedup 1.0000x reference)
//
#include <hip/hip_runtime.h>
#include <hip/hip_bf16.h>
#include <math.h>

#define EPSF 1e-5f

constexpr int D = 128;   // feature dim
constexpr int K = 128;   // centroids
constexpr int TILE_ROWS = 64;        // 4 waves x 16 rows per block

typedef __bf16 bf16x8 __attribute__((ext_vector_type(8)));
typedef float  f32x4  __attribute__((ext_vector_type(4)));

// ---------------- kernel 1: centroid exp-map -> bf16 + c2 ----------------
__global__ __launch_bounds__(64) void prep_kernel(const float* __restrict__ w,
                                                  __bf16* __restrict__ crb,
                                                  float* __restrict__ c2) {
    int k = blockIdx.x;
    int t = threadIdx.x;
    float a = w[k * D + t];
    float b = w[k * D + t + 64];
    float ss = a * a + b * b;
#pragma unroll
    for (int off = 1; off < 64; off <<= 1)
        ss += __shfl_xor(ss, off, 64);
    float nrm   = sqrtf(ss);
    float nclip = fmaxf(nrm, EPSF);
    float targ  = fminf(nclip, 15.0f);
    float th    = tanhf(targ);
    float s     = th / nclip;
    crb[k * D + t]      = (__bf16)(a * s);
    crb[k * D + t + 64] = (__bf16)(b * s);
    if (t == 0) {
        float cn = s * nrm;
        c2[k] = cn * cn;
    }
}

// ---------------- kernel 2: LDS-free MFMA pairwise distance ----------------
// One 64-row tile per block (3125 blocks, proven dispatch mode). NO B staging:
// crb is 32KB = one L1, so B-fragments are read straight from global (L1-hit
// after the first touch). x loads are NONTEMPORAL so streaming x doesn't evict
// B from L1. LDS use is 2.1KB (end-of-block column reduce only) -> occupancy
// is VGPR-bound, not LDS-bound.
// Lessons encoded:
//  - R1/R2: no cross-tile register prefetch (spills -> +300MB HBM traffic).
//  - R3: no min-waves qualifier on __launch_bounds__ (clamps to 64 arch VGPRs
//    and scratch-thrashes).
//  - R4/R5/R6: resident waves is the first-order knob; LDS B-staging capped
//    blocks/CU at 4 and bought nothing. sched_barrier(0) per s-group caps the
//    B-load hoisting window (~8 loads / 32 VGPRs) to keep VGPR <= 128.
__global__ __launch_bounds__(256) void main_kernel(
        const float* __restrict__ x, const float* __restrict__ mask,
        const __bf16* __restrict__ crb, const float* __restrict__ c2g,
        float* __restrict__ out_node, float* __restrict__ partial,
        float* __restrict__ maskpart, int ntiles) {
    __shared__ float sCol[4][K];
    __shared__ float sM[4];

    const int t    = threadIdx.x;
    const int wave = t >> 6;
    const int lane = t & 63;
    const int m    = lane & 15;
    const int q    = lane >> 4;
    const int rowbase = blockIdx.x * TILE_ROWS + wave * 16;

    // ---- c2 for this lane's 8 columns (registers, no LDS) ----
    float c2v[8];
#pragma unroll
    for (int tk = 0; tk < 8; tk++) c2v[tk] = c2g[tk * 16 + m];

    // ---- x rows: two half-batches (caps x-phase liveness at 4 float4).
    //      NT loads keep streamed x out of L1 so B stays resident. ----
    const float* xrow = x + (size_t)(rowbase + m) * D + q * 8;
    float ssq = 0.f;
    bf16x8 av[4];
#pragma unroll
    for (int h = 0; h < 2; h++) {
        f32x4 xr[4];
#pragma unroll
        for (int s2 = 0; s2 < 2; s2++) {
            int s = h * 2 + s2;
            xr[2 * s2]     = __builtin_nontemporal_load((const f32x4*)(xrow + s * 32));
            xr[2 * s2 + 1] = __builtin_nontemporal_load((const f32x4*)(xrow + s * 32 + 4));
        }
#pragma unroll
        for (int s2 = 0; s2 < 2; s2++) {
            int s = h * 2 + s2;
            f32x4 a0 = xr[2 * s2], a1 = xr[2 * s2 + 1];
            ssq += a0[0]*a0[0] + a0[1]*a0[1] + a0[2]*a0[2] + a0[3]*a0[3]
                 + a1[0]*a1[0] + a1[1]*a1[1] + a1[2]*a1[2] + a1[3]*a1[3];
            av[s][0] = (__bf16)a0[0]; av[s][1] = (__bf16)a0[1];
            av[s][2] = (__bf16)a0[2]; av[s][3] = (__bf16)a0[3];
            av[s][4] = (__bf16)a1[0]; av[s][5] = (__bf16)a1[1];
            av[s][6] = (__bf16)a1[2]; av[s][7] = (__bf16)a1[3];
        }
    }
    float mk = __builtin_nontemporal_load(mask + rowbase + m);

    // lanes {l, l^16, l^32, l^48} hold partials of the same row
    ssq += __shfl_xor(ssq, 16, 64);
    ssq += __shfl_xor(ssq, 32, 64);
    // mask sum over the wave's 16 rows
    float mred = mk;
    mred += __shfl_xor(mred, 1, 64);
    mred += __shfl_xor(mred, 2, 64);
    mred += __shfl_xor(mred, 4, 64);
    mred += __shfl_xor(mred, 8, 64);
    // distribute row quantities to C-layout owner lanes
    float x2r[4], pxr[4], mvr[4];
#pragma unroll
    for (int i = 0; i < 4; i++) {
        x2r[i] = __shfl(ssq, q * 4 + i, 64);
        pxr[i] = 1.0f - x2r[i];
        mvr[i] = __shfl(mk, q * 4 + i, 64);
    }

    // ---- MFMA: B-frags straight from global (L1-hit). sched_barrier per
    //      s-group caps the load-hoisting window at 8 loads = 32 VGPRs. ----
    f32x4 acc[8] = {};
#pragma unroll
    for (int s = 0; s < 4; s++) {
#pragma unroll
        for (int tk = 0; tk < 8; tk++) {
            bf16x8 bv = *(const bf16x8*)(crb + (size_t)(tk * 16 + m) * D + q * 8 + s * 32);
            acc[tk] = __builtin_amdgcn_mfma_f32_16x16x32_bf16(av[s], bv, acc[tk], 0, 0, 0);
        }
        __builtin_amdgcn_sched_barrier(0);
    }

    // ---- epilogue IN PLACE: acc[tk][i] := masked distance ----
    float colsum[8];
#pragma unroll
    for (int tk = 0; tk < 8; tk++) {
        float c2c = c2v[tk];
        float pc  = 1.0f - c2c;
        colsum[tk] = 0.f;
#pragma unroll
        for (int i = 0; i < 4; i++) {
            float dot = acc[tk][i];
            float sq  = fmaxf(x2r[i] + c2c - 2.0f * dot, 0.0f);
            float den = fmaxf(pxr[i] * pc, EPSF);
            float arg = fmaf(2.0f * sq, __builtin_amdgcn_rcpf(den), 1.0f);
            arg = fmaxf(arg, 1.0f + 1e-7f);
            float dist = __logf(arg + __builtin_amdgcn_sqrtf(fmaf(arg, arg, -1.0f)));
            float val = dist * mvr[i];
            acc[tk][i] = val;
            colsum[tk] += val;
        }
    }

    // ---- single tight 32-store burst (proven write-combining) ----
    const int rowq = rowbase + q * 4;
    float* obase = out_node + (size_t)rowq * K + m;
#pragma unroll
    for (int tk = 0; tk < 8; tk++) {
#pragma unroll
        for (int i = 0; i < 4; i++)
            __builtin_nontemporal_store(acc[tk][i], obase + (size_t)i * K + tk * 16);
    }

    // ---- column partials across the 4 quads, then cross-wave via LDS ----
#pragma unroll
    for (int tk = 0; tk < 8; tk++) {
        colsum[tk] += __shfl_xor(colsum[tk], 16, 64);
        colsum[tk] += __shfl_xor(colsum[tk], 32, 64);
    }
    if (lane < 16) {
#pragma unroll
        for (int tk = 0; tk < 8; tk++)
            sCol[wave][tk * 16 + lane] = colsum[tk];
    }
    if (lane == 0) sM[wave] = mred;

    __syncthreads();   // only LDS writes pending -> cheap drain

    if (t < K)
        partial[(size_t)blockIdx.x * K + t] =
            sCol[0][t] + sCol[1][t] + sCol[2][t] + sCol[3][t];
    if (t == 0)
        maskpart[blockIdx.x] = sM[0] + sM[1] + sM[2] + sM[3];
}

// ---------------- kernel 3: column reduce + divide by mask sum ----------------
__global__ __launch_bounds__(256) void reduce_kernel(
        const float* __restrict__ partial, const float* __restrict__ maskpart,
        float* __restrict__ out_graph, int NB) {
    int k = blockIdx.x;
    int t = threadIdx.x;
    float s = 0.f, mm = 0.f;
    for (int b = t; b < NB; b += 256) {
        s  += partial[(size_t)b * K + k];
        mm += maskpart[b];
    }
#pragma unroll
    for (int off = 1; off < 64; off <<= 1) {
        s  += __shfl_xor(s, off, 64);
        mm += __shfl_xor(mm, off, 64);
    }
    __shared__ float rs[4], rm[4];
    int w = t >> 6;
    if ((t & 63) == 0) { rs[w] = s; rm[w] = mm; }
    __syncthreads();
    if (t == 0) {
        float st = rs[0] + rs[1] + rs[2] + rs[3];
        float mt = rm[0] + rm[1] + rm[2] + rm[3];
        out_graph[k] = st / mt;
    }
}

extern "C" void kernel_launch(void* const* d_in, const int* in_sizes, int n_in,
                              void* d_out, int out_size, void* d_ws, size_t ws_size,
                              hipStream_t stream) {
    const float* node = (const float*)d_in[0];   // [N, D]
    const float* mask = (const float*)d_in[1];   // [N, 1]
    const float* w    = (const float*)d_in[2];   // [K, D]
    float* out = (float*)d_out;

    int N  = in_sizes[0] / D;                    // 200000
    int NB = N / TILE_ROWS;                      // 3125 (exact)

    // ws layout: crb bf16[K*D] | c2[K] | partial[NB*K] | maskpart[NB]
    __bf16* crb     = (__bf16*)d_ws;
    float* c2       = (float*)(crb + K * D);
    float* partial  = c2 + K;
    float* maskpart = partial + (size_t)NB * K;

    float* out_graph = out;        // [K]
    float* out_node  = out + K;    // [N, K]

    prep_kernel<<<K, 64, 0, stream>>>(w, crb, c2);
    main_kernel<<<NB, 256, 0, stream>>>(node, mask, crb, c2, out_node,
                                        partial, maskpart, NB);
    reduce_kernel<<<K, 256, 0, stream>>>(partial, maskpart, out_graph, NB);
}